// Round 3
// baseline (148.815 us; speedup 1.0000x reference)
//
#include <hip/hip_runtime.h>

// Depthwise Gaussian blur K=121, replicate pad, separable.
// R3: ONE streaming kernel used twice. Each pass = vertical 1D conv with a
// 16-row ping-pong float4 register window fed directly from global (clamped
// row index per load -> replicate pad), output written TRANSPOSED so the
// second pass is again a coalesced vertical conv and layout is restored.
// No data-staging LDS, no big barriers, high occupancy, loads stream.

#define WW    512
#define HH    512
#define PLANE (512 * 512)
#define NIMG  24
#define RAD   60

// Normalized 1D gaussian in LDS (128 taps, 121..127 exactly 0).
__device__ __forceinline__ void make_weights(const float* __restrict__ sigma,
                                             float* __restrict__ wlds, int tid) {
    const float s = sigma[0] * 8.0f + 16.0f;
    const float inv2v = 1.0f / (2.0f * s * s);
    float sum = 0.0f;
    #pragma unroll
    for (int k = 0; k <= 120; ++k) {
        const float c = (float)k - 60.0f;
        sum += __expf(-c * c * inv2v);
    }
    if (tid < 128) {
        float g = 0.0f;
        if (tid < 121) {
            const float c = (float)tid - 60.0f;
            g = __expf(-c * c * inv2v);
        }
        wlds[tid] = g / sum;
    }
}

// One octet of taps: prefetch next 8 window rows from GLOBAL (clamped),
// accumulate 8 taps x 8 output rows x float4 cols.
#define OCT(CUR, NXT, KO)                                                   \
    { *(float4*)&wq[0] = *(const float4*)&wlds[(KO) * 8];                   \
      *(float4*)&wq[4] = *(const float4*)&wlds[(KO) * 8 + 4];               \
      _Pragma("unroll")                                                     \
      for (int ki = 0; ki < 8; ++ki) {                                      \
          int rr = r0 - 52 + (KO) * 8 + ki;                                 \
          rr = rr < 0 ? 0 : (rr > HH - 1 ? HH - 1 : rr);                    \
          NXT[ki] = *(const float4*)&src[(size_t)rr * WW];                  \
          const float wk = wq[ki];                                          \
          _Pragma("unroll")                                                 \
          for (int j = 0; j < 8; ++j) {                                     \
              const int idx = ki + j;                                       \
              const float4 v = (idx < 8) ? CUR[idx] : NXT[idx - 8];         \
              acc[j].x += wk * v.x; acc[j].y += wk * v.y;                   \
              acc[j].z += wk * v.z; acc[j].w += wk * v.w;                   \
          }                                                                 \
      }                                                                     \
    }

// Store 8 rows x 1 col of acc component CC transposed: outT[col+CC][r0..r0+7]
#define STORE_T(CC, COMP)                                                   \
    { float4 lo = make_float4(acc[0].COMP, acc[1].COMP,                     \
                              acc[2].COMP, acc[3].COMP);                    \
      float4 hi = make_float4(acc[4].COMP, acc[5].COMP,                     \
                              acc[6].COMP, acc[7].COMP);                    \
      float* p = dst + (size_t)(col + (CC)) * WW + r0;                      \
      *(float4*)p       = lo;                                               \
      *(float4*)(p + 4) = hi; }

__global__ __launch_bounds__(256, 3) void blur_vt(
        const float* __restrict__ in, const float* __restrict__ sigma,
        float* __restrict__ outT) {
    __shared__ float wlds[128];
    const int tid  = threadIdx.x;
    const int quad = tid & 127;              // 128 float4 col-groups = 512 cols
    const int g8   = tid >> 7;               // 0..1 row granule
    const int col  = quad * 4;
    const int r0   = blockIdx.x * 16 + g8 * 8;
    const float* __restrict__ src = in + (size_t)blockIdx.y * PLANE + col;

    float4 wa[8], wb[8], acc[8];
    float  wq[8];

    // init window: taps 0..7 -> rows r0-60 .. r0-53 (clamped low only)
    #pragma unroll
    for (int m = 0; m < 8; ++m) {
        int rr = r0 - 60 + m;
        rr = rr < 0 ? 0 : rr;
        wa[m] = *(const float4*)&src[(size_t)rr * WW];
    }
    make_weights(sigma, wlds, tid);
    #pragma unroll
    for (int j = 0; j < 8; ++j) acc[j] = make_float4(0.f, 0.f, 0.f, 0.f);
    __syncthreads();

    #pragma unroll 1
    for (int ko = 0; ko < 16; ko += 2) {     // 128 taps, ping-pong window
        OCT(wa, wb, ko)
        OCT(wb, wa, ko + 1)
    }

    float* __restrict__ dst = outT + (size_t)blockIdx.y * PLANE;
    STORE_T(0, x)
    STORE_T(1, y)
    STORE_T(2, z)
    STORE_T(3, w)
}

extern "C" void kernel_launch(void* const* d_in, const int* in_sizes, int n_in,
                              void* d_out, int out_size, void* d_ws, size_t ws_size,
                              hipStream_t stream) {
    const float* x     = (const float*)d_in[0];
    const float* sigma = (const float*)d_in[1];
    float* out = (float*)d_out;
    float* tmp = (float*)d_ws;               // transposed intermediate, 25.2 MB

    const dim3 grid(HH / 16, NIMG);
    // pass 1: vertical blur of x  -> tmp (transposed)
    blur_vt<<<grid, dim3(256), 0, stream>>>(x, sigma, tmp);
    // pass 2: "vertical" blur of tmp == horizontal blur -> out (transposed back)
    blur_vt<<<grid, dim3(256), 0, stream>>>(tmp, sigma, out);
}

// Round 4
// 119.815 us; speedup vs baseline: 1.2420x; 1.2420x over previous
//
#include <hip/hip_runtime.h>

// Depthwise Gaussian blur K=121, replicate pad, separable, fp32.
// R4: blur_v = R2's known-good LDS-staged kernel. blur_h rebuilt: 16 outputs
// per lane with a 4-octet rotating register window (prefetch dist 1) ->
// window LDS traffic halves per output; 8 rows/block; 81x12-float padded row
// (972 stride) for uniform banks + safe last-prefetch overrun.

#define HH   512
#define WW   512
#define PLANE (512 * 512)
#define NIMG 24
#define RAD  60

__device__ __forceinline__ void make_weights(const float* __restrict__ sigma,
                                             float* __restrict__ wlds, int tid) {
    const float s = sigma[0] * 8.0f + 16.0f;
    const float inv2v = 1.0f / (2.0f * s * s);
    float sum = 0.0f;
    #pragma unroll
    for (int k = 0; k <= 120; ++k) {
        const float c = (float)k - 60.0f;
        sum += __expf(-c * c * inv2v);
    }
    if (tid < 128) {
        float g = 0.0f;
        if (tid < 121) {
            const float c = (float)tid - 60.0f;
            g = __expf(-c * c * inv2v);
        }
        wlds[tid] = g / sum;   // taps 121..127 exactly 0
    }
}

// ---------------- vertical pass (unchanged from R2) --------------------------
#define V_OCT(CUR, NXT, KO)                                               \
    { *(float4*)&wq[0] = *(const float4*)&wlds[(KO) * 8];                 \
      *(float4*)&wq[4] = *(const float4*)&wlds[(KO) * 8 + 4];             \
      _Pragma("unroll")                                                   \
      for (int ki = 0; ki < 8; ++ki) {                                    \
          NXT[ki] = sm4[(r0 + ((KO) + 1) * 8 + ki) * 8 + tx];             \
          const float wk = wq[ki];                                        \
          _Pragma("unroll")                                               \
          for (int j = 0; j < 8; ++j) {                                   \
              const int idx = ki + j;                                     \
              const float4 v = (idx < 8) ? CUR[idx] : NXT[idx - 8];       \
              acc[j].x += wk * v.x; acc[j].y += wk * v.y;                 \
              acc[j].z += wk * v.z; acc[j].w += wk * v.w;                 \
          }                                                               \
      }                                                                   \
    }

__global__ __launch_bounds__(256, 3) void blur_v(
        const float* __restrict__ x, const float* __restrict__ sigma,
        float* __restrict__ tmp) {
    __shared__ float sm[384 * 32];                   // 48 KB -> 3 blocks/CU
    __shared__ float wlds[128];
    const int tid = threadIdx.x;
    const int w0  = blockIdx.x * 32;
    const int h0  = blockIdx.y * 256;
    const float* __restrict__ src = x + (size_t)blockIdx.z * PLANE;

    {
        const int fc = (tid & 7) * 4;
        int r = tid >> 3;
        #pragma unroll
        for (int it = 0; it < 12; ++it, r += 32) {
            int gr = h0 - RAD + r;
            gr = gr < 0 ? 0 : (gr > HH - 1 ? HH - 1 : gr);
            *(float4*)&sm[r * 32 + fc] =
                *(const float4*)&src[(size_t)gr * WW + w0 + fc];
        }
    }
    make_weights(sigma, wlds, tid);
    __syncthreads();

    const int tx = tid & 7;
    const int r0 = (tid >> 3) * 8;
    const float4* __restrict__ sm4 = (const float4*)sm;

    float4 acc[8];
    #pragma unroll
    for (int j = 0; j < 8; ++j) acc[j] = make_float4(0.f, 0.f, 0.f, 0.f);

    float4 wa[8], wb[8];
    float  wq[8];
    #pragma unroll
    for (int m = 0; m < 8; ++m) wa[m] = sm4[(r0 + m) * 8 + tx];

    #pragma unroll 1
    for (int ko = 0; ko < 16; ko += 2) {
        V_OCT(wa, wb, ko)
        V_OCT(wb, wa, ko + 1)
    }

    float* __restrict__ dst = tmp + (size_t)blockIdx.z * PLANE;
    #pragma unroll
    for (int j = 0; j < 8; ++j)
        *(float4*)&dst[(size_t)(h0 + r0 + j) * WW + w0 + tx * 4] = acc[j];
}

// ---------------- horizontal pass (R4) ---------------------------------------
// 8 rows/block, full 512-wide. Halo 648 cols staged as 81 groups of
// (8 real + 4 pad) floats -> row stride 972. Lane (tid&31) computes 16
// consecutive cols of row (tid>>5); 4-octet rotating window, prefetch 1.
#define HPG_ROW 972    // 81 groups * 12 floats

#define LOADG(DST, G)                                                     \
    { *(float4*)&DST[0] = *(const float4*)&bs[(G) * 12];                  \
      *(float4*)&DST[4] = *(const float4*)&bs[(G) * 12 + 4]; }

#define H_OCT(W0, W1, W2, W3, KO)                                         \
    { LOADG(W3, (KO) + 3)                                                 \
      *(float4*)&wq[0] = *(const float4*)&wlds[(KO) * 8];                 \
      *(float4*)&wq[4] = *(const float4*)&wlds[(KO) * 8 + 4];             \
      _Pragma("unroll")                                                   \
      for (int ki = 0; ki < 8; ++ki) {                                    \
          const float wk = wq[ki];                                        \
          _Pragma("unroll")                                               \
          for (int j = 0; j < 16; ++j) {                                  \
              const int idx = ki + j;                                     \
              const float v = (idx < 8) ? W0[idx]                         \
                            : (idx < 16) ? W1[idx - 8] : W2[idx - 16];    \
              acc[j] += wk * v;                                           \
          }                                                               \
      }                                                                   \
    }

__global__ __launch_bounds__(256, 4) void blur_h(
        const float* __restrict__ tmp, const float* __restrict__ sigma,
        float* __restrict__ out) {
    __shared__ float sm[8 * HPG_ROW];                // 31.1 KB
    __shared__ float wlds[128];
    const int tid = threadIdx.x;
    const int h0  = blockIdx.x * 8;
    const float* __restrict__ src = tmp + (size_t)blockIdx.y * PLANE;

    #pragma unroll
    for (int it = 0; it < 3; ++it) {                 // 648 halo cols staged
        const int c = tid + it * 256;
        if (c < 648) {
            int gc = c - RAD;
            gc = gc < 0 ? 0 : (gc > WW - 1 ? WW - 1 : gc);
            const int la = ((c >> 3) * 12) + (c & 7);
            #pragma unroll
            for (int r = 0; r < 8; ++r)
                sm[r * HPG_ROW + la] = src[(size_t)(h0 + r) * WW + gc];
        }
    }
    make_weights(sigma, wlds, tid);
    __syncthreads();

    const int r    = tid >> 5;                       // 0..7
    const int L    = tid & 31;                       // cols 16L..16L+15
    const float* __restrict__ bs = sm + r * HPG_ROW + L * 24;  // group 2L

    float w0[8], w1[8], w2[8], w3[8], wq[8];
    float acc[16];
    #pragma unroll
    for (int j = 0; j < 16; ++j) acc[j] = 0.0f;

    LOADG(w0, 0)
    LOADG(w1, 1)
    LOADG(w2, 2)

    #pragma unroll 1
    for (int ko = 0; ko < 16; ko += 4) {             // 4-buffer rotation
        H_OCT(w0, w1, w2, w3, ko)
        H_OCT(w1, w2, w3, w0, ko + 1)
        H_OCT(w2, w3, w0, w1, ko + 2)
        H_OCT(w3, w0, w1, w2, ko + 3)
    }

    float* __restrict__ dst = out + (size_t)blockIdx.y * PLANE
                                  + (size_t)(h0 + r) * WW + L * 16;
    *(float4*)(dst)      = make_float4(acc[0],  acc[1],  acc[2],  acc[3]);
    *(float4*)(dst + 4)  = make_float4(acc[4],  acc[5],  acc[6],  acc[7]);
    *(float4*)(dst + 8)  = make_float4(acc[8],  acc[9],  acc[10], acc[11]);
    *(float4*)(dst + 12) = make_float4(acc[12], acc[13], acc[14], acc[15]);
}

// ---------------- launch -----------------------------------------------------
extern "C" void kernel_launch(void* const* d_in, const int* in_sizes, int n_in,
                              void* d_out, int out_size, void* d_ws, size_t ws_size,
                              hipStream_t stream) {
    const float* x     = (const float*)d_in[0];
    const float* sigma = (const float*)d_in[1];
    float* out = (float*)d_out;
    float* tmp = (float*)d_ws;                       // 25.2 MB intermediate

    blur_v<<<dim3(WW / 32, HH / 256, NIMG), dim3(256), 0, stream>>>(x, sigma, tmp);
    blur_h<<<dim3(HH / 8, NIMG), dim3(256), 0, stream>>>(tmp, sigma, out);
}